// Round 13
// baseline (95.100 us; speedup 1.0000x reference)
//
#include <hip/hip_runtime.h>
#include <math.h>

// Batched tridiagonal solve A(exp(alpha)) u = f_rhs via chunked partition
// (SPIKE-style), one row per wave, CS=16.
// Round 13: division-free continuants + Green's-function recovery.
//  - phase 1: dual 3-term continuant chains (delta,phi,psi fwd; rev mirror):
//    pure-fma 4cy/step dependency, 2 rcps total (was 32 chained rcp+NR).
//    Triplets: (De,Ae,Be)=(phi15,psi15,K16*d14)/d15; (Ds,As,Bs)=
//    (phiR0, a0*dR1, psiR0)/dR0. Verified vs r9 algebra on n=1,2 + boundaries.
//  - phase 2: f64 projective scan VERBATIM r9/r12 (f32 FAILED r7).
//  - phase 3: u_i = [dR_{i+1}*sL_i + dL_{i-1}*K_{i+1}*sR_{i+1}]/Delta.
//    Fwd pass stores dL,sL (32 regs, post-scan only — scan-time live stays
//    ~45 like r9, the only clean-VGPR round); bwd pass pure fma, u emitted
//    off-chain. uL/uR enter as chain inits (exact linearity).
//  - ranges: |sum log| <= ~24 over 16 steps -> delta in [1e-11,1e15], f32-safe.
//  - WPB=8 (f_lds amortized), per-wave ostage + wave-local waitcnt drain.
// Spill tell (r12): WRITE_SIZE 90MB vs clean 65.6MB. Watch it.

constexpr int BT   = 16384;
constexpr int MPTS = 1024;
constexpr int NU   = 1023;   // real unknowns
constexpr int CS   = 16;     // chunk size (per lane)
constexpr int WPB  = 8;      // waves (rows) per block

__device__ __forceinline__ float frcp(float x) {
    float r = __builtin_amdgcn_rcpf(x);        // v_rcp_f32
    r = fmaf(r, fmaf(-x, r, 1.0f), r);         // 1 NR -> ~0.5 ulp
    return r;
}
__device__ __forceinline__ double drcp(double x) {
    double r = __builtin_amdgcn_rcp(x);        // v_rcp_f64, ~2^-27
    r = fma(r, fma(-x, r, 1.0), r);            // 1 NR -> ~2^-54
    return r;
}
__device__ __forceinline__ int sw(int j) { return j + (j >> 5); }

__global__ __launch_bounds__(WPB * 64, 6)
void pt_kernel(const float* __restrict__ alpha,
               const float* __restrict__ f_rhs,
               float* __restrict__ out) {
    const int t    = threadIdx.x;
    const int lane = t & 63;
    const int w    = t >> 6;
    const int row  = blockIdx.x * WPB + w;
    const int s    = lane * CS;          // first global index of this chunk

    __shared__ float f_lds[1056];            // swizzled: h2*f[j] at sw(j)
    __shared__ float ostage[WPB][1056];      // per-wave output stage

    const float h2 = (float)(1.0 / (1023.0 * 1023.0));
    for (int i = t; i < NU; i += WPB * 64) f_lds[sw(i)] = h2 * f_rhs[i];
    if (t == 0) f_lds[sw(1023)] = 0.0f;      // identity-pad row: f = 0

    // ---------------- load K = exp(alpha) for this chunk (17 values) --------
    const float* arow = alpha + (size_t)row * MPTS;
    float kf[CS + 1];
    #pragma unroll
    for (int q = 0; q < 4; ++q) {
        const float4 v = *reinterpret_cast<const float4*>(arow + s + 4 * q);
        kf[4 * q + 0] = expf(v.x);
        kf[4 * q + 1] = expf(v.y);
        kf[4 * q + 2] = expf(v.z);
        kf[4 * q + 3] = expf(v.w);
    }
    {
        float kx = (lane < 63) ? arow[s + CS] : 0.0f;  // lane63: exp(0)=1
        kf[CS] = expf(kx);
    }
    // lane 63 pre-patch: K_{1023} := 0 makes row j=1022 {b=K1022, d=0} and
    // row j=1023 the identity pad {a=0 (kc=0), b=0+exp(0)=1, f=0}.
    if (lane == 63) kf[15] = 0.0f;

    __syncthreads();  // f_lds ready

    // ---------------- phase 1: dual division-free continuant chains ---------
    // Row i: -K_i u_{i-1} + (K_i+K_{i+1}) u_i - K_{i+1} u_{i+1} = f_i.
    // fwd:  d_i = b_i d_{i-1} - K_i^2 d_{i-2}; p_i = K_i p_{i-1} + f_i d_{i-1};
    //       s_i = K_i s_{i-1}.
    // rev:  dR_i = b_i dR_{i+1} - K_{i+1}^2 dR_{i+2};
    //       pR_i = K_{i+1} pR_{i+1} + f_i dR_{i+1}; sR_i = K_{i+1} sR_{i+1}.
    const float a0v = (lane == 0) ? 0.0f : kf[0];
    float dl2 = 0.0f, dl1 = 1.0f, ph1 = 0.0f, ps1 = 1.0f;
    float rd2 = 0.0f, rd1 = 1.0f, rph = 0.0f, rps = 1.0f;
    float d14 = 1.0f, rd1s = 1.0f;
    #pragma unroll
    for (int i = 0; i < CS; ++i) {
        // fwd at i
        {
            float b = kf[i] + kf[i + 1];
            if (i == 0) b = (lane == 0) ? (b + kf[0]) : b;  // j=0: b=2K0+K1
            const float tq = kf[i] * kf[i];
            const float f  = f_lds[sw(s + i)];
            const float dn = fmaf(b, dl1, -(tq * dl2));
            const float pn = fmaf(kf[i], ph1, f * dl1);
            const float sn = kf[i] * ps1;
            if (i == CS - 1) d14 = dl1;     // delta^L_14
            dl2 = dl1; dl1 = dn; ph1 = pn; ps1 = sn;
        }
        // rev at ir = 15 - i
        {
            const int ir = CS - 1 - i;
            float b = kf[ir] + kf[ir + 1];
            if (ir == 0) b = (lane == 0) ? (b + kf[0]) : b;
            const float tq = kf[ir + 1] * kf[ir + 1];
            const float f  = f_lds[sw(s + ir)];
            const float dn = fmaf(b, rd1, -(tq * rd2));
            const float pn = fmaf(kf[ir + 1], rph, f * rd1);
            const float sn = kf[ir + 1] * rps;
            if (ir == 1) rd1s = dn;         // delta^R_1
            rd2 = rd1; rd1 = dn; rph = pn; rps = sn;
        }
    }
    // Triplets: u_e = De + Ae*uL + Be*uR ; u_s = Ds + As*uL + Bs*uR
    const float rf = frcp(dl1);             // 1/delta^L_15
    const float De_f = ph1 * rf;
    const float Ae_f = ps1 * rf;
    float Be_f = (kf[CS] * d14) * rf;
    Be_f = (lane == 63) ? 0.0f : Be_f;      // pad row decouples
    const float rr = frcp(rd1);             // 1/delta^R_0
    const float Ds_f = rph * rr;
    const float Bs_f = rps * rr;
    const float As_f = (a0v * rd1s) * rr;

    // ---------------- phase 2: reduced boundary system (f64) ----------------
    // y_p = Ds + As*x_{p-1} + Bs*y_{p+1};  x_p = De + Ae*x_{p-1} + Be*y_{p+1}
    // Projective 3x3 suffix scan, kept normalized so m22 == 1 (6 entries).
    const double Ds = (double)Ds_f, As = (double)As_f, Bs = (double)Bs_f;
    const double De = (double)De_f, Ae = (double)Ae_f, Be = (double)Be_f;
    double m00 = Bs;
    double m01 = fma(Bs, De, -(Ds * Be));
    double m02 = Ds;
    double m11 = fma(Bs, Ae, -(As * Be));
    double m12 = As;
    double m21 = -Be;

    #pragma unroll
    for (int dlt = 1; dlt < 64; dlt <<= 1) {
        const bool val = (lane + dlt) < 64;
        double b00 = __shfl_down(m00, dlt); b00 = val ? b00 : 1.0;
        double b01 = __shfl_down(m01, dlt); b01 = val ? b01 : 0.0;
        double b02 = __shfl_down(m02, dlt); b02 = val ? b02 : 0.0;
        double b11 = __shfl_down(m11, dlt); b11 = val ? b11 : 1.0;
        double b12 = __shfl_down(m12, dlt); b12 = val ? b12 : 0.0;
        double b21 = __shfl_down(m21, dlt); b21 = val ? b21 : 0.0;
        const double n00 = m00 * b00;
        const double n01 = fma(m00, b01, fma(m01, b11, m02 * b21));
        const double n02 = fma(m00, b02, fma(m01, b12, m02));   // b22 == 1
        const double n11 = fma(m11, b11, m12 * b21);
        const double n12 = fma(m11, b12, m12);
        const double n21 = fma(m21, b11, b21);                  // m22 == 1
        const double n22 = fma(m21, b12, 1.0);
        const double rn = drcp(n22);       // n22 in (0,1]: strict dominance
        m00 = n00 * rn; m01 = n01 * rn; m02 = n02 * rn;
        m11 = n11 * rn; m12 = n12 * rn; m21 = n21 * rn;
    }
    // y_p = alf + bet * x_{p-1}   (m22 == 1)
    const double alf = m02;
    const double bet = m12;
    double alfn = __shfl_down(alf, 1); alfn = (lane == 63) ? 0.0 : alfn;
    double betn = __shfl_down(bet, 1); betn = (lane == 63) ? 0.0 : betn;

    // x_p = dl + gm * x_{p-1}
    const double tt = drcp(fma(-Be, betn, 1.0));
    const double dl = fma(Be, alfn, De) * tt;
    const double gm = Ae * tt;

    // Affine prefix scan for x (x_{-1} = 0).
    double X = dl, G = gm;
    #pragma unroll
    for (int dlt = 1; dlt < 64; dlt <<= 1) {
        double bx = __shfl_up(X, dlt);
        double bg = __shfl_up(G, dlt);
        const bool val = lane >= dlt;
        bx = val ? bx : 0.0;
        bg = val ? bg : 1.0;
        X = fma(G, bx, X);
        G = G * bg;
    }
    double xp = __shfl_up(X, 1);
    const double uLd = (lane == 0) ? 0.0 : xp;          // u_{s-1}
    const double Y   = fma(bet, uLd, alf);              // y_p = u_s
    double yn = __shfl_down(Y, 1);
    const double uRd = (lane == 63) ? 0.0 : yn;         // u_{s+16}

    // ---------------- phase 3: Green's-function recovery (f32) --------------
    // u_i = [dR_{i+1}*sL_i + dL_{i-1}*K_{i+1}*sR_{i+1}] / Delta
    // sL: sigma^L_i = K_i sigma^L_{i-1} + f_i dL_{i-1},  sigma^L_{-1} = uL
    // sR: sigma^R_i = K_{i+1} sigma^R_{i+1} + f_i dR_{i+1}, sigma^R_16 = uR
    const float uL = (float)uLd;
    const float uR = (float)uRd;
    float dL[CS], sL[CS];
    {
        float d2 = 0.0f, d1 = 1.0f, sg = uL;
        #pragma unroll
        for (int i = 0; i < CS; ++i) {
            float b = kf[i] + kf[i + 1];
            if (i == 0) b = (lane == 0) ? (b + kf[0]) : b;
            const float tq = kf[i] * kf[i];
            const float f  = f_lds[sw(s + i)];
            dL[i] = d1;                                  // delta^L_{i-1}
            const float dn = fmaf(b, d1, -(tq * d2));
            const float sn = fmaf(kf[i], sg, f * d1);
            sL[i] = sn;                                  // sigma^L_i
            d2 = d1; d1 = dn; sg = sn;
        }
        // d1 = delta^L_15 = Delta
        const float invD = frcp(d1);
        float rdd2 = 0.0f, rdd1 = 1.0f, sr = uR;
        float* ost = ostage[w];
        #pragma unroll
        for (int i = 0; i < CS; ++i) {
            const int ir = CS - 1 - i;
            const float p  = kf[ir + 1] * sr;            // d_ir * sigma^R_{ir+1}
            const float uu = fmaf(rdd1, sL[ir], dL[ir] * p) * invD;
            ost[sw(s + ir)] = uu;
            float b = kf[ir] + kf[ir + 1];
            if (ir == 0) b = (lane == 0) ? (b + kf[0]) : b;
            const float tq = kf[ir + 1] * kf[ir + 1];
            const float f  = f_lds[sw(s + ir)];
            const float dn = fmaf(b, rdd1, -(tq * rdd2));
            sr = fmaf(kf[ir + 1], sr, f * rdd1);         // sigma^R_ir
            rdd2 = rdd1; rdd1 = dn;
        }
    }
    // ostage[w] is wave-private; DS ops are in-order per wave. lgkmcnt(0)
    // orders write -> read without an 8-wave block barrier.
    asm volatile("s_waitcnt lgkmcnt(0)" ::: "memory");

    // Coalesced output: 64 lanes x 4B contiguous per instruction.
    float* ost = ostage[w];
    float* orow = out + (size_t)row * NU;
    #pragma unroll
    for (int it = 0; it < 16; ++it) {
        const int c = it * 64 + lane;
        if (c < NU) orow[c] = ost[sw(c)];
    }
}

extern "C" void kernel_launch(void* const* d_in, const int* in_sizes, int n_in,
                              void* d_out, int out_size, void* d_ws, size_t ws_size,
                              hipStream_t stream) {
    const float* alpha = (const float*)d_in[0];
    const float* f_rhs = (const float*)d_in[1];
    float* out = (float*)d_out;

    dim3 grid(BT / WPB), block(WPB * 64);
    pt_kernel<<<grid, block, 0, stream>>>(alpha, f_rhs, out);
}

// Round 14
// 42.289 us; speedup vs baseline: 2.2488x; 2.2488x over previous
//
#include <hip/hip_runtime.h>
#include <math.h>

// Batched tridiagonal solve A(exp(alpha)) u = f_rhs via chunked partition
// (SPIKE-style). Round 14: TWO rows per wave, TIME-interleaved (intra-wave
// ILP) — the one untried axis after 6 variants pinned at ~39us:
//  - clean rounds (r6/r9/r11, WRITE=65.6MB) all ~39us at VALUBusy 33-48%
//    => latency-bound at 3-4 resident waves/SIMD. r11 cut instructions
//    (lane-split) -> no gain (halved waves); r12/r13 raised occupancy ->
//    spilled (WRITE 90/302MB). This round doubles per-wave ILP instead.
//  - K in LDS (klds[8][1058], expf'd once): kills kf[17] register arrays;
//    backsub overwrites klds in place (K dead by then) => doubles as the
//    output stage; no separate ostage. LDS 38KB -> 4 blocks/CU.
//  - numerics VERBATIM r9 (proven absmax 3.66e-4): dual 3-scalar f32
//    phase-1 chains (now x2 rows = 4 chains interleaved), f64 projective
//    scan (x2, A/B statement-interleaved, named scalars only — r13 showed
//    arrays crossing phases go to scratch), per-row f32 re-solve phase 3
//    with locally-created c3/u3 (r9's clean-register pattern).
//  - launch_bounds(256,4): VGPR cap 128 >> ~85 peak live. Spill tell:
//    WRITE_SIZE 65.6MB clean vs 90/302MB when spilling.

constexpr int BT   = 16384;
constexpr int MPTS = 1024;
constexpr int NU   = 1023;   // real unknowns
constexpr int CS   = 16;     // chunk size (per lane)
constexpr int WPB  = 4;      // waves per block
constexpr int RPB  = 8;      // rows per block (2 per wave)

__device__ __forceinline__ float frcp(float x) {
    float r = __builtin_amdgcn_rcpf(x);        // v_rcp_f32
    r = fmaf(r, fmaf(-x, r, 1.0f), r);         // 1 NR -> ~0.5 ulp
    return r;
}
__device__ __forceinline__ double drcp(double x) {
    double r = __builtin_amdgcn_rcp(x);        // v_rcp_f64, ~2^-27
    r = fma(r, fma(-x, r, 1.0), r);            // 1 NR -> ~2^-54
    return r;
}
__device__ __forceinline__ int sw(int j) { return j + (j >> 5); }

__global__ __launch_bounds__(256, 4)
void pt_kernel(const float* __restrict__ alpha,
               const float* __restrict__ f_rhs,
               float* __restrict__ out) {
    const int t    = threadIdx.x;
    const int lane = t & 63;
    const int w    = t >> 6;
    const int rowA = blockIdx.x * RPB + 2 * w;
    const int rowB = rowA + 1;
    const int s    = lane * CS;          // first global index of this chunk

    __shared__ float f_lds[1056];        // swizzled: h2*f[j] at sw(j)
    __shared__ float klds[RPB][1058];    // swizzled K per row; sw(1024)=1056

    const float h2 = (float)(1.0 / (1023.0 * 1023.0));
    for (int i = t; i < NU; i += 256) f_lds[sw(i)] = h2 * f_rhs[i];
    if (t == 0) f_lds[sw(1023)] = 0.0f;  // identity-pad row: f = 0

    float* klA = klds[2 * w];
    float* klB = klds[2 * w + 1];
    {
        const float* ar = alpha + (size_t)rowA * MPTS;
        const float* br = alpha + (size_t)rowB * MPTS;
        #pragma unroll
        for (int q = 0; q < 4; ++q) {
            const int j0 = s + 4 * q;
            const float4 va = *reinterpret_cast<const float4*>(ar + j0);
            const float4 vb = *reinterpret_cast<const float4*>(br + j0);
            klA[sw(j0 + 0)] = expf(va.x); klA[sw(j0 + 1)] = expf(va.y);
            klA[sw(j0 + 2)] = expf(va.z); klA[sw(j0 + 3)] = expf(va.w);
            klB[sw(j0 + 0)] = expf(vb.x); klB[sw(j0 + 1)] = expf(vb.y);
            klB[sw(j0 + 2)] = expf(vb.z); klB[sw(j0 + 3)] = expf(vb.w);
        }
        if (lane == 63) {
            // K[1023]:=0 decouples row 1022 and makes j=1023 the identity
            // pad row; K[1024]:=1 is lane63's "kf[16]" (exp(0)).
            klA[sw(1023)] = 0.0f; klA[sw(1024)] = 1.0f;
            klB[sw(1023)] = 0.0f; klB[sw(1024)] = 1.0f;
        }
    }
    __syncthreads();  // f_lds + klds ready (cross-lane reads below)

    const float k0A = klA[sw(s)], k16A = klA[sw(s + 16)];
    const float k0B = klB[sw(s)], k16B = klB[sw(s + 16)];

    // ---------------- phase 1: 4 interleaved 3-scalar chains ----------------
    // fwd: at i=15 -> (De,Ae,Be). rev: at ir=0 -> (Ds,Bs,As). [r9 verbatim]
    float cFA = (lane == 0) ? 1.0f : 0.0f, uFA = 0.0f, vFA = 1.0f, kcFA = k0A;
    float cFB = (lane == 0) ? 1.0f : 0.0f, uFB = 0.0f, vFB = 1.0f, kcFB = k0B;
    float uRvA = 0.0f, vRvA = 1.0f, wRvA = 0.0f, knRA = k16A;
    float uRvB = 0.0f, vRvB = 1.0f, wRvB = 0.0f, knRB = k16B;
    #pragma unroll
    for (int i = 0; i < CS; ++i) {
        const int j  = s + i;
        const int jr = s + (CS - 1 - i);
        const float fj = f_lds[sw(j)];
        const float fr = f_lds[sw(jr)];
        // fwd A
        {
            const float kn = klA[sw(j + 1)];
            const float b  = kcFA + kn;
            const float den = fmaf(kcFA, cFA, b);
            const float r   = frcp(den);
            float ci = -kn * r;
            if (i == CS - 1) ci = (lane == 63) ? 0.0f : ci;
            uFA = fmaf(kcFA, uFA, fj) * r;
            vFA = (kcFA * vFA) * r;
            cFA = ci; kcFA = kn;
        }
        // fwd B
        {
            const float kn = klB[sw(j + 1)];
            const float b  = kcFB + kn;
            const float den = fmaf(kcFB, cFB, b);
            const float r   = frcp(den);
            float ci = -kn * r;
            if (i == CS - 1) ci = (lane == 63) ? 0.0f : ci;
            uFB = fmaf(kcFB, uFB, fj) * r;
            vFB = (kcFB * vFB) * r;
            cFB = ci; kcFB = kn;
        }
        // rev A (boundary j=0 at i==CS-1 & lane 0: b=2K0+K1, a=0)
        {
            const float kcr = klA[sw(jr)];
            float b   = kcr + knRA;
            float kcm = kcr;
            if (i == CS - 1) {
                b   = (lane == 0) ? (b + kcr) : b;
                kcm = (lane == 0) ? 0.0f : kcr;
            }
            const float den = fmaf(-knRA, wRvA, b);
            const float r   = frcp(den);
            uRvA = fmaf(knRA, uRvA, fr) * r;
            vRvA = (knRA * vRvA) * r;
            wRvA = kcm * r;
            knRA = kcr;
        }
        // rev B
        {
            const float kcr = klB[sw(jr)];
            float b   = kcr + knRB;
            float kcm = kcr;
            if (i == CS - 1) {
                b   = (lane == 0) ? (b + kcr) : b;
                kcm = (lane == 0) ? 0.0f : kcr;
            }
            const float den = fmaf(-knRB, wRvB, b);
            const float r   = frcp(den);
            uRvB = fmaf(knRB, uRvB, fr) * r;
            vRvB = (knRB * vRvB) * r;
            wRvB = kcm * r;
            knRB = kcr;
        }
    }

    // ---------------- phase 2: dual f64 projective scans (interleaved) ------
    const double DsA = (double)uRvA, AsA = (double)wRvA, BsA = (double)vRvA;
    const double DeA = (double)uFA,  AeA = (double)vFA,  BeA = -(double)cFA;
    const double DsB = (double)uRvB, AsB = (double)wRvB, BsB = (double)vRvB;
    const double DeB = (double)uFB,  AeB = (double)vFB,  BeB = -(double)cFB;

    double mA00 = BsA, mA01 = fma(BsA, DeA, -(DsA * BeA)), mA02 = DsA;
    double mA11 = fma(BsA, AeA, -(AsA * BeA)), mA12 = AsA, mA21 = -BeA;
    double mB00 = BsB, mB01 = fma(BsB, DeB, -(DsB * BeB)), mB02 = DsB;
    double mB11 = fma(BsB, AeB, -(AsB * BeB)), mB12 = AsB, mB21 = -BeB;

    #pragma unroll
    for (int dlt = 1; dlt < 64; dlt <<= 1) {
        const bool val = (lane + dlt) < 64;
        double a00 = __shfl_down(mA00, dlt); a00 = val ? a00 : 1.0;
        double b00 = __shfl_down(mB00, dlt); b00 = val ? b00 : 1.0;
        double a01 = __shfl_down(mA01, dlt); a01 = val ? a01 : 0.0;
        double b01 = __shfl_down(mB01, dlt); b01 = val ? b01 : 0.0;
        double a02 = __shfl_down(mA02, dlt); a02 = val ? a02 : 0.0;
        double b02 = __shfl_down(mB02, dlt); b02 = val ? b02 : 0.0;
        double a11 = __shfl_down(mA11, dlt); a11 = val ? a11 : 1.0;
        double b11 = __shfl_down(mB11, dlt); b11 = val ? b11 : 1.0;
        double a12 = __shfl_down(mA12, dlt); a12 = val ? a12 : 0.0;
        double b12 = __shfl_down(mB12, dlt); b12 = val ? b12 : 0.0;
        double a21 = __shfl_down(mA21, dlt); a21 = val ? a21 : 0.0;
        double b21 = __shfl_down(mB21, dlt); b21 = val ? b21 : 0.0;

        const double nA00 = mA00 * a00;
        const double nB00 = mB00 * b00;
        const double nA01 = fma(mA00, a01, fma(mA01, a11, mA02 * a21));
        const double nB01 = fma(mB00, b01, fma(mB01, b11, mB02 * b21));
        const double nA02 = fma(mA00, a02, fma(mA01, a12, mA02));  // a22==1
        const double nB02 = fma(mB00, b02, fma(mB01, b12, mB02));
        const double nA11 = fma(mA11, a11, mA12 * a21);
        const double nB11 = fma(mB11, b11, mB12 * b21);
        const double nA12 = fma(mA11, a12, mA12);
        const double nB12 = fma(mB11, b12, mB12);
        const double nA21 = fma(mA21, a11, a21);                   // m22==1
        const double nB21 = fma(mB21, b11, b21);
        const double nA22 = fma(mA21, a12, 1.0);
        const double nB22 = fma(mB21, b12, 1.0);
        const double rnA = drcp(nA22);     // n22 in (0,1]: strict dominance
        const double rnB = drcp(nB22);
        mA00 = nA00 * rnA; mA01 = nA01 * rnA; mA02 = nA02 * rnA;
        mA11 = nA11 * rnA; mA12 = nA12 * rnA; mA21 = nA21 * rnA;
        mB00 = nB00 * rnB; mB01 = nB01 * rnB; mB02 = nB02 * rnB;
        mB11 = nB11 * rnB; mB12 = nB12 * rnB; mB21 = nB21 * rnB;
    }
    // y_p = alf + bet * x_{p-1}   (m22 == 1)
    const double alfA = mA02, betA = mA12;
    const double alfB = mB02, betB = mB12;
    double alfnA = __shfl_down(alfA, 1); alfnA = (lane == 63) ? 0.0 : alfnA;
    double betnA = __shfl_down(betA, 1); betnA = (lane == 63) ? 0.0 : betnA;
    double alfnB = __shfl_down(alfB, 1); alfnB = (lane == 63) ? 0.0 : alfnB;
    double betnB = __shfl_down(betB, 1); betnB = (lane == 63) ? 0.0 : betnB;

    const double ttA = drcp(fma(-BeA, betnA, 1.0));
    const double ttB = drcp(fma(-BeB, betnB, 1.0));
    const double dlA = fma(BeA, alfnA, DeA) * ttA;
    const double dlB = fma(BeB, alfnB, DeB) * ttB;
    const double gmA = AeA * ttA;
    const double gmB = AeB * ttB;

    // Affine prefix scans for x (x_{-1} = 0), interleaved.
    double XA = dlA, GA = gmA, XB = dlB, GB = gmB;
    #pragma unroll
    for (int dlt = 1; dlt < 64; dlt <<= 1) {
        double bxA = __shfl_up(XA, dlt);
        double bxB = __shfl_up(XB, dlt);
        double bgA = __shfl_up(GA, dlt);
        double bgB = __shfl_up(GB, dlt);
        const bool val = lane >= dlt;
        bxA = val ? bxA : 0.0;  bgA = val ? bgA : 1.0;
        bxB = val ? bxB : 0.0;  bgB = val ? bgB : 1.0;
        XA = fma(GA, bxA, XA);  GA = GA * bgA;
        XB = fma(GB, bxB, XB);  GB = GB * bgB;
    }
    double xpA = __shfl_up(XA, 1);
    double xpB = __shfl_up(XB, 1);
    const double uLdA = (lane == 0) ? 0.0 : xpA;
    const double uLdB = (lane == 0) ? 0.0 : xpB;
    const double YA = fma(betA, uLdA, alfA);
    const double YB = fma(betB, uLdB, alfB);
    double ynA = __shfl_down(YA, 1);
    double ynB = __shfl_down(YB, 1);
    const double uRdA = (lane == 63) ? 0.0 : ynA;
    const double uRdB = (lane == 63) ? 0.0 : ynB;

    // ---------------- phase 3 + drain, row A then row B ---------------------
    // Re-solve with uL/uR folded into f (r9 verbatim); backsub overwrites
    // klds in place (K dead); wave-local lgkmcnt orders write->read.
    {
        const float uL = (float)uLdA, uR = (float)uRdA;
        float c3[CS], u3[CS];
        float cp = (lane == 0) ? 1.0f : 0.0f, up = 0.0f, kc = k0A;
        #pragma unroll
        for (int i = 0; i < CS; ++i) {
            const float kn = klA[sw(s + i + 1)];
            const float b  = kc + kn;
            float f = f_lds[sw(s + i)];
            if (i == 0)      f = fmaf(k0A,  uL, f);   // lane0: uL==0
            if (i == CS - 1) f = fmaf(k16A, uR, f);   // lane63: uR==0
            const float den = fmaf(kc, cp, b);
            const float r   = frcp(den);
            const float ci = -kn * r;
            const float ui = fmaf(kc, up, f) * r;
            c3[i] = ci; u3[i] = ui;
            cp = ci; up = ui; kc = kn;
        }
        float un = u3[CS - 1];
        klA[sw(s + CS - 1)] = un;
        #pragma unroll
        for (int i = CS - 2; i >= 0; --i) {
            un = fmaf(-c3[i], un, u3[i]);
            klA[sw(s + i)] = un;
        }
    }
    asm volatile("s_waitcnt lgkmcnt(0)" ::: "memory");
    {
        float* orow = out + (size_t)rowA * NU;
        #pragma unroll
        for (int it = 0; it < 16; ++it) {
            const int c = it * 64 + lane;
            if (c < NU) orow[c] = klA[sw(c)];
        }
    }
    {
        const float uL = (float)uLdB, uR = (float)uRdB;
        float c3[CS], u3[CS];
        float cp = (lane == 0) ? 1.0f : 0.0f, up = 0.0f, kc = k0B;
        #pragma unroll
        for (int i = 0; i < CS; ++i) {
            const float kn = klB[sw(s + i + 1)];
            const float b  = kc + kn;
            float f = f_lds[sw(s + i)];
            if (i == 0)      f = fmaf(k0B,  uL, f);
            if (i == CS - 1) f = fmaf(k16B, uR, f);
            const float den = fmaf(kc, cp, b);
            const float r   = frcp(den);
            const float ci = -kn * r;
            const float ui = fmaf(kc, up, f) * r;
            c3[i] = ci; u3[i] = ui;
            cp = ci; up = ui; kc = kn;
        }
        float un = u3[CS - 1];
        klB[sw(s + CS - 1)] = un;
        #pragma unroll
        for (int i = CS - 2; i >= 0; --i) {
            un = fmaf(-c3[i], un, u3[i]);
            klB[sw(s + i)] = un;
        }
    }
    asm volatile("s_waitcnt lgkmcnt(0)" ::: "memory");
    {
        float* orow = out + (size_t)rowB * NU;
        #pragma unroll
        for (int it = 0; it < 16; ++it) {
            const int c = it * 64 + lane;
            if (c < NU) orow[c] = klB[sw(c)];
        }
    }
}

extern "C" void kernel_launch(void* const* d_in, const int* in_sizes, int n_in,
                              void* d_out, int out_size, void* d_ws, size_t ws_size,
                              hipStream_t stream) {
    const float* alpha = (const float*)d_in[0];
    const float* f_rhs = (const float*)d_in[1];
    float* out = (float*)d_out;

    dim3 grid(BT / RPB), block(WPB * 64);
    pt_kernel<<<grid, block, 0, stream>>>(alpha, f_rhs, out);
}